// Round 14
// baseline (440.076 us; speedup 1.0000x reference)
//
#include <hip/hip_runtime.h>
#include <hip/hip_bf16.h>
#include <math.h>

typedef float f4 __attribute__((ext_vector_type(4)));

#define FMA __builtin_fmaf

#define BATCH 64
#define PP 500
#define NN 501

// ---------------- merged projections: blocks 0..499 -> Q, 500..1000 -> K/V ----
__global__ __launch_bounds__(256) void k_proj(
    const float* __restrict__ Xq, const float* __restrict__ Ld,
    const float* __restrict__ Xn, const float* __restrict__ Wq,
    const float* __restrict__ Wk, const float* __restrict__ Wv,
    float* __restrict__ Q, float* __restrict__ K_, float* __restrict__ V_)
{
  __shared__ float xs[64*132];
  const int t = threadIdx.x;
  const int tr = t >> 5, tc = t & 31;
  if (blockIdx.x < 500) {
    const int r0 = blockIdx.x * 64;
    for (int i = t; i < 64*32; i += 256) {
      int r = i >> 5, k4 = (i & 31) << 2;
      *(f4*)(xs + r*132 + k4) = *(const f4*)(Xq + (size_t)(r0+r)*128 + k4);
    }
    if (t < 64) xs[t*132 + 128] = Ld[r0 + t];
    __syncthreads();
    float acc[8][4];
    #pragma unroll
    for (int i = 0; i < 8; i++)
      #pragma unroll
      for (int c = 0; c < 4; c++) acc[i][c] = 0.f;
    for (int k4 = 0; k4 < 128; k4 += 4) {
      f4 x[8], w[4];
      #pragma unroll
      for (int j = 0; j < 4; j++) w[j] = *(const f4*)(Wq + (size_t)(k4+j)*128 + tc*4);
      #pragma unroll
      for (int i = 0; i < 8; i++) x[i] = *(const f4*)(xs + (tr*8+i)*132 + k4);
      #pragma unroll
      for (int i = 0; i < 8; i++)
        #pragma unroll
        for (int j = 0; j < 4; j++)
          #pragma unroll
          for (int c = 0; c < 4; c++)
            acc[i][c] = FMA(x[i][j], w[j][c], acc[i][c]);
    }
    {
      f4 w = *(const f4*)(Wq + (size_t)128*128 + tc*4);
      #pragma unroll
      for (int i = 0; i < 8; i++) {
        float xv = xs[(tr*8+i)*132 + 128];
        #pragma unroll
        for (int c = 0; c < 4; c++) acc[i][c] = FMA(xv, w[c], acc[i][c]);
      }
    }
    #pragma unroll
    for (int i = 0; i < 8; i++) {
      f4 o;
      #pragma unroll
      for (int c = 0; c < 4; c++) o[c] = acc[i][c];
      *(f4*)(Q + (size_t)(r0 + tr*8 + i)*128 + tc*4) = o;
    }
  } else {
    const int r0 = (blockIdx.x - 500) * 64;
    for (int i = t; i < 64*32; i += 256) {
      int r = i >> 5, k4 = (i & 31) << 2;
      *(f4*)(xs + r*132 + k4) = *(const f4*)(Xn + (size_t)(r0+r)*128 + k4);
    }
    __syncthreads();
    float accK[8][4], accV[8][4];
    #pragma unroll
    for (int i = 0; i < 8; i++)
      #pragma unroll
      for (int c = 0; c < 4; c++) { accK[i][c] = 0.f; accV[i][c] = 0.f; }
    for (int k4 = 0; k4 < 128; k4 += 4) {
      f4 x[8], wk[4], wv[4];
      #pragma unroll
      for (int j = 0; j < 4; j++) {
        wk[j] = *(const f4*)(Wk + (size_t)(k4+j)*128 + tc*4);
        wv[j] = *(const f4*)(Wv + (size_t)(k4+j)*128 + tc*4);
      }
      #pragma unroll
      for (int i = 0; i < 8; i++) x[i] = *(const f4*)(xs + (tr*8+i)*132 + k4);
      #pragma unroll
      for (int i = 0; i < 8; i++)
        #pragma unroll
        for (int j = 0; j < 4; j++)
          #pragma unroll
          for (int c = 0; c < 4; c++) {
            accK[i][c] = FMA(x[i][j], wk[j][c], accK[i][c]);
            accV[i][c] = FMA(x[i][j], wv[j][c], accV[i][c]);
          }
    }
    #pragma unroll
    for (int i = 0; i < 8; i++) {
      f4 ok, ov;
      #pragma unroll
      for (int c = 0; c < 4; c++) { ok[c] = accK[i][c]; ov[c] = accV[i][c]; }
      *(f4*)(K_ + (size_t)(r0 + tr*8 + i)*128 + tc*4) = ok;
      *(f4*)(V_ + (size_t)(r0 + tr*8 + i)*128 + tc*4) = ov;
    }
  }
}

// ---------------- mega-fused: attn (v8) + ffn + final per (b, 32-row) tile --
// Grid 1024 = 64 b x 16 ptiles. LDS union: sA = ks->xs->ms, sB = vs->hs->es,
// mks attn-only. Phases separated by barriers; each phase body is the proven
// kernel at 32-row granularity. No OC/MH global round trips.
__global__ __launch_bounds__(256, 3) void k_fused(
    const float* __restrict__ Q, const float* __restrict__ K_, const float* __restrict__ V_,
    const float* __restrict__ Msk, const float* __restrict__ EN,
    const float* __restrict__ Wn, const float* __restrict__ Bn,
    const float* __restrict__ Wn2, const float* __restrict__ Bn2,
    const float* __restrict__ Wm, const float* __restrict__ Bm,
    float* __restrict__ OUT)
{
  __shared__ float sA[32*132];   // ks | xs | ms   16.9 KB
  __shared__ float sB[32*132];   // vs | hs | es   16.9 KB
  __shared__ float mks[32*33];   // attn mask      4.2 KB
  const int blk = blockIdx.x;
  const int b  = blk >> 4;
  const int pt = blk & 15;
  const int p0 = pt * 32;
  const int nv = min(32, PP - p0);
  const int t = threadIdx.x;

  // ================= phase 1: attention (v8 body) =================
  {
    const int h   = t >> 5;
    const int row = t & 31;
    const bool pvalid = (p0 + row) < PP;
    const int p = pvalid ? (p0 + row) : (PP - 1);

    f4 q0, q1, q2, q3;
    {
      const float* qrow = Q + ((size_t)b*PP + p)*128 + h*16;
      q0 = *(const f4*)(qrow);
      q1 = *(const f4*)(qrow + 4);
      q2 = *(const f4*)(qrow + 8);
      q3 = *(const f4*)(qrow + 12);
    }
    const int mr = t >> 3, nq = (t & 7) << 2;
    const int grow = min(p0 + mr, PP - 1);
    const float* gm = Msk + ((size_t)b*PP + grow)*NN;

    float m_r = -1e30f, l_r = 0.f;
    f4 o0 = {0.f,0.f,0.f,0.f}, o1 = o0, o2 = o0, o3 = o0;

    f4 kpre[4], vpre[4]; float mk[4];
    #pragma unroll
    for (int u = 0; u < 4; u++) {
      int i = t + u*256;
      int n = i >> 5, d4 = (i & 31) << 2;
      kpre[u] = *(const f4*)(K_ + ((size_t)b*NN + n)*128 + d4);
      vpre[u] = *(const f4*)(V_ + ((size_t)b*NN + n)*128 + d4);
    }
    #pragma unroll
    for (int j = 0; j < 4; j++)
      mk[j] = (nq + j < NN) ? gm[nq + j] : -1e30f;

    for (int c0 = 0; c0 < NN; c0 += 32) {
      #pragma unroll
      for (int u = 0; u < 4; u++) {
        int i = t + u*256;
        int n = i >> 5, d4 = (i & 31) << 2;
        *(f4*)(sA + n*132 + d4) = kpre[u];
        *(f4*)(sB + n*132 + d4) = vpre[u];
      }
      {
        float* dm = mks + mr*33 + nq;
        #pragma unroll
        for (int j = 0; j < 4; j++) dm[j] = mk[j];
      }
      __syncthreads();

      const int c1 = c0 + 32;
      if (c1 < NN) {
        #pragma unroll
        for (int u = 0; u < 4; u++) {
          int i = t + u*256;
          int n = i >> 5, d4 = (i & 31) << 2;
          int ng = c1 + n;
          f4 kv = {0.f,0.f,0.f,0.f}, vv = {0.f,0.f,0.f,0.f};
          if (ng < NN) {
            kv = *(const f4*)(K_ + ((size_t)b*NN + ng)*128 + d4);
            vv = *(const f4*)(V_ + ((size_t)b*NN + ng)*128 + d4);
          }
          kpre[u] = kv; vpre[u] = vv;
        }
        #pragma unroll
        for (int j = 0; j < 4; j++)
          mk[j] = (c1 + nq + j < NN) ? gm[c1 + nq + j] : -1e30f;
      }

      const float* ksh = sA + h*16;
      const float* vsh = sB + h*16;
      const float* mrw = mks + row*33;
      #pragma unroll
      for (int n = 0; n < 32; n++) {
        const float* kf = ksh + n*132;
        f4 k0 = *(const f4*)(kf);
        f4 k1 = *(const f4*)(kf + 4);
        f4 k2 = *(const f4*)(kf + 8);
        f4 k3 = *(const f4*)(kf + 12);
        float s = 0.f;
        #pragma unroll
        for (int d = 0; d < 4; d++) s = FMA(q0[d], k0[d], s);
        #pragma unroll
        for (int d = 0; d < 4; d++) s = FMA(q1[d], k1[d], s);
        #pragma unroll
        for (int d = 0; d < 4; d++) s = FMA(q2[d], k2[d], s);
        #pragma unroll
        for (int d = 0; d < 4; d++) s = FMA(q3[d], k3[d], s);
        s = FMA(s, 0.25f, mrw[n]);
        if (s > m_r) {
          float cc = __expf(m_r - s);
          m_r = s;
          l_r *= cc;
          o0 *= cc; o1 *= cc; o2 *= cc; o3 *= cc;
        }
        float e = __expf(s - m_r);
        l_r += e;
        const float* vf = vsh + n*132;
        f4 v0 = *(const f4*)(vf);
        f4 v1 = *(const f4*)(vf + 4);
        f4 v2 = *(const f4*)(vf + 8);
        f4 v3 = *(const f4*)(vf + 12);
        #pragma unroll
        for (int d = 0; d < 4; d++) {
          o0[d] = FMA(e, v0[d], o0[d]);
          o1[d] = FMA(e, v1[d], o1[d]);
          o2[d] = FMA(e, v2[d], o2[d]);
          o3[d] = FMA(e, v3[d], o3[d]);
        }
      }
      __syncthreads();
    }

    // write attn output tile into sA (xs layout [32][132]); no global OC
    float inv = 1.f / l_r;
    float* xr = sA + row*132 + h*16;
    *(f4*)(xr)      = o0 * inv;
    *(f4*)(xr + 4)  = o1 * inv;
    *(f4*)(xr + 8)  = o2 * inv;
    *(f4*)(xr + 12) = o3 * inv;
  }
  __syncthreads();   // xs complete

  // ================= phase 2: FFN chain (k_ffn body @32 rows) =================
  const int tr = t >> 5, tc = t & 31;
  {
    // GEMM1: relu(xs @ new[b] + bias) -> hs (sB)
    {
      const float* W1 = Wn + (size_t)b*16384;
      float acc[4][4];
      #pragma unroll
      for (int i = 0; i < 4; i++)
        #pragma unroll
        for (int c = 0; c < 4; c++) acc[i][c] = 0.f;
      for (int k4 = 0; k4 < 128; k4 += 4) {
        f4 x[4], w[4];
        #pragma unroll
        for (int j = 0; j < 4; j++) w[j] = *(const f4*)(W1 + (size_t)(k4+j)*128 + tc*4);
        #pragma unroll
        for (int i = 0; i < 4; i++) x[i] = *(const f4*)(sA + (tr*4+i)*132 + k4);
        #pragma unroll
        for (int i = 0; i < 4; i++)
          #pragma unroll
          for (int j = 0; j < 4; j++)
            #pragma unroll
            for (int c = 0; c < 4; c++)
              acc[i][c] = FMA(x[i][j], w[j][c], acc[i][c]);
      }
      f4 b1 = *(const f4*)(Bn + b*128 + tc*4);
      #pragma unroll
      for (int i = 0; i < 4; i++) {
        f4 o;
        #pragma unroll
        for (int c = 0; c < 4; c++) o[c] = fmaxf(acc[i][c] + b1[c], 0.f);
        *(f4*)(sB + (tr*4+i)*132 + tc*4) = o;
      }
    }
    __syncthreads();
    // GEMM2: hs @ new_2[b] + bias2 + residual(xs)
    float h2[4][4];
    {
      const float* W2 = Wn2 + (size_t)b*16384;
      float acc[4][4];
      #pragma unroll
      for (int i = 0; i < 4; i++)
        #pragma unroll
        for (int c = 0; c < 4; c++) acc[i][c] = 0.f;
      for (int k4 = 0; k4 < 128; k4 += 4) {
        f4 x[4], w[4];
        #pragma unroll
        for (int j = 0; j < 4; j++) w[j] = *(const f4*)(W2 + (size_t)(k4+j)*128 + tc*4);
        #pragma unroll
        for (int i = 0; i < 4; i++) x[i] = *(const f4*)(sB + (tr*4+i)*132 + k4);
        #pragma unroll
        for (int i = 0; i < 4; i++)
          #pragma unroll
          for (int j = 0; j < 4; j++)
            #pragma unroll
            for (int c = 0; c < 4; c++)
              acc[i][c] = FMA(x[i][j], w[j][c], acc[i][c]);
      }
      f4 b2 = *(const f4*)(Bn2 + b*128 + tc*4);
      #pragma unroll
      for (int i = 0; i < 4; i++)
        #pragma unroll
        for (int c = 0; c < 4; c++)
          h2[i][c] = acc[i][c] + b2[c] + sA[(tr*4+i)*132 + tc*4 + c];
    }
    __syncthreads();
    #pragma unroll
    for (int i = 0; i < 4; i++) {
      f4 o;
      #pragma unroll
      for (int c = 0; c < 4; c++) o[c] = h2[i][c];
      *(f4*)(sB + (tr*4+i)*132 + tc*4) = o;
    }
    __syncthreads();
    // GEMM3: hs @ mhc_W + mhc_b -> ms (sA; xs dead after GEMM2 residual)
    {
      float acc[4][4];
      #pragma unroll
      for (int i = 0; i < 4; i++)
        #pragma unroll
        for (int c = 0; c < 4; c++) acc[i][c] = 0.f;
      for (int k4 = 0; k4 < 128; k4 += 4) {
        f4 x[4], w[4];
        #pragma unroll
        for (int j = 0; j < 4; j++) w[j] = *(const f4*)(Wm + (size_t)(k4+j)*128 + tc*4);
        #pragma unroll
        for (int i = 0; i < 4; i++) x[i] = *(const f4*)(sB + (tr*4+i)*132 + k4);
        #pragma unroll
        for (int i = 0; i < 4; i++)
          #pragma unroll
          for (int j = 0; j < 4; j++)
            #pragma unroll
            for (int c = 0; c < 4; c++)
              acc[i][c] = FMA(x[i][j], w[j][c], acc[i][c]);
      }
      f4 b3 = *(const f4*)(Bm + tc*4);
      #pragma unroll
      for (int i = 0; i < 4; i++) {
        f4 o;
        #pragma unroll
        for (int c = 0; c < 4; c++) o[c] = acc[i][c] + b3[c];
        *(f4*)(sA + (tr*4+i)*132 + tc*4) = o;
      }
    }
  }
  __syncthreads();   // ms complete; hs dead

  // ================= phase 3: final (k_final body, 16 x 32-col EN tiles) ======
  {
    const float* enb = EN + (size_t)b*NN*128;
    // prologue: EN tile 0 -> regs (32 rows x 128 = 1024 f4, 4/thread)
    f4 epre[4];
    #pragma unroll
    for (int u = 0; u < 4; u++) {
      int i = t + u*256;
      int n = i >> 5, k4 = (i & 31) << 2;
      f4 v = {0.f,0.f,0.f,0.f};
      if (n < NN) v = *(const f4*)(enb + (size_t)n*128 + k4);
      epre[u] = v;
    }
    float s[16][4];
    #pragma unroll
    for (int nt = 0; nt < 16; nt++) {
      #pragma unroll
      for (int u = 0; u < 4; u++) {
        int i = t + u*256;
        int n = i >> 5, k4 = (i & 31) << 2;
        *(f4*)(sB + n*132 + k4) = epre[u];
      }
      __syncthreads();
      if (nt < 15) {
        const int n1 = (nt+1)*32;
        #pragma unroll
        for (int u = 0; u < 4; u++) {
          int i = t + u*256;
          int n = i >> 5, k4 = (i & 31) << 2;
          f4 v = {0.f,0.f,0.f,0.f};
          if (n1 + n < NN) v = *(const f4*)(enb + (size_t)(n1+n)*128 + k4);
          epre[u] = v;
        }
      }
      float acc[4];
      #pragma unroll
      for (int i = 0; i < 4; i++) acc[i] = 0.f;
      #pragma unroll 8
      for (int k4 = 0; k4 < 128; k4 += 4) {
        f4 x[4];
        #pragma unroll
        for (int i = 0; i < 4; i++) x[i] = *(const f4*)(sA + (tr*4+i)*132 + k4);
        f4 e0 = *(const f4*)(sB + tc*132 + k4);
        #pragma unroll
        for (int i = 0; i < 4; i++)
          #pragma unroll
          for (int j = 0; j < 4; j++)
            acc[i] = FMA(x[i][j], e0[j], acc[i]);
      }
      #pragma unroll
      for (int i = 0; i < 4; i++) s[nt][i] = acc[i];
      __syncthreads();
    }
    // clip + mask (mask rows L2-hot from attn phase)
    const float* mkb = Msk + (size_t)(b*PP + p0)*NN;
    #pragma unroll
    for (int nt = 0; nt < 16; nt++)
      #pragma unroll
      for (int i = 0; i < 4; i++) {
        int r = tr*4 + i, n = nt*32 + tc;
        float val = -INFINITY;
        if (r < nv && n < NN) {
          float E = __expf(s[nt][i] * 0.17677669529663687f);
          val = 10.f - 20.f/(E + 1.f) + mkb[(size_t)r*NN + n];
        }
        s[nt][i] = val;
      }
    // per-row softmax (width-32 shfl across tc)
    float* ob = OUT + (size_t)(b*PP + p0)*NN;
    #pragma unroll
    for (int i = 0; i < 4; i++) {
      float m = -INFINITY;
      #pragma unroll
      for (int nt = 0; nt < 16; nt++) m = fmaxf(m, s[nt][i]);
      #pragma unroll
      for (int o = 16; o > 0; o >>= 1) m = fmaxf(m, __shfl_xor(m, o, 32));
      float l = 0.f;
      #pragma unroll
      for (int nt = 0; nt < 16; nt++) {
        float e_ = __expf(s[nt][i] - m);
        s[nt][i] = e_;
        l += e_;
      }
      #pragma unroll
      for (int o = 16; o > 0; o >>= 1) l += __shfl_xor(l, o, 32);
      const int r = tr*4 + i;
      if (r < nv) {
        float inv = 1.f / l;
        float* orow = ob + (size_t)r*NN;
        #pragma unroll
        for (int nt = 0; nt < 16; nt++) {
          int n = nt*32 + tc;
          if (n < NN) orow[n] = s[nt][i] * inv;
        }
      }
    }
  }
}

extern "C" void kernel_launch(void* const* d_in, const int* in_sizes, int n_in,
                              void* d_out, int out_size, void* d_ws, size_t ws_size,
                              hipStream_t stream) {
  const float* eln  = (const float*)d_in[0];
  const float* load = (const float*)d_in[1];
  const float* mask = (const float*)d_in[2];
  const float* en   = (const float*)d_in[3];
  const float* Wq   = (const float*)d_in[4];
  const float* Wk   = (const float*)d_in[5];
  const float* Wv   = (const float*)d_in[6];
  const float* Wm   = (const float*)d_in[7];
  const float* Bm   = (const float*)d_in[8];
  const float* Wn   = (const float*)d_in[9];
  const float* Bn   = (const float*)d_in[10];
  const float* Wn2  = (const float*)d_in[11];
  const float* Bn2  = (const float*)d_in[12];
  float* out = (float*)d_out;
  float* ws  = (float*)d_ws;
  float* Q   = ws;
  float* K_  = ws + 4096000;     // 64*500*128
  float* V_  = ws + 8200192;     // + 64*501*128
  hipLaunchKernelGGL(k_proj,  dim3(1001), dim3(256), 0, stream, eln, load, en, Wq, Wk, Wv, Q, K_, V_);
  hipLaunchKernelGGL(k_fused, dim3(1024), dim3(256), 0, stream, Q, K_, V_, mask, en,
                     Wn, Bn, Wn2, Bn2, Wm, Bm, out);
}

// Round 15
// 393.482 us; speedup vs baseline: 1.1184x; 1.1184x over previous
//
#include <hip/hip_runtime.h>
#include <hip/hip_bf16.h>
#include <math.h>

typedef float f4 __attribute__((ext_vector_type(4)));

#define FMA __builtin_fmaf

#define BATCH 64
#define PP 500
#define NN 501

// ---------------- merged projections: blocks 0..499 -> Q, 500..1000 -> K/V ----
__global__ __launch_bounds__(256) void k_proj(
    const float* __restrict__ Xq, const float* __restrict__ Ld,
    const float* __restrict__ Xn, const float* __restrict__ Wq,
    const float* __restrict__ Wk, const float* __restrict__ Wv,
    float* __restrict__ Q, float* __restrict__ K_, float* __restrict__ V_)
{
  __shared__ float xs[64*132];
  const int t = threadIdx.x;
  const int tr = t >> 5, tc = t & 31;
  if (blockIdx.x < 500) {
    const int r0 = blockIdx.x * 64;
    for (int i = t; i < 64*32; i += 256) {
      int r = i >> 5, k4 = (i & 31) << 2;
      *(f4*)(xs + r*132 + k4) = *(const f4*)(Xq + (size_t)(r0+r)*128 + k4);
    }
    if (t < 64) xs[t*132 + 128] = Ld[r0 + t];
    __syncthreads();
    float acc[8][4];
    #pragma unroll
    for (int i = 0; i < 8; i++)
      #pragma unroll
      for (int c = 0; c < 4; c++) acc[i][c] = 0.f;
    for (int k4 = 0; k4 < 128; k4 += 4) {
      f4 x[8], w[4];
      #pragma unroll
      for (int j = 0; j < 4; j++) w[j] = *(const f4*)(Wq + (size_t)(k4+j)*128 + tc*4);
      #pragma unroll
      for (int i = 0; i < 8; i++) x[i] = *(const f4*)(xs + (tr*8+i)*132 + k4);
      #pragma unroll
      for (int i = 0; i < 8; i++)
        #pragma unroll
        for (int j = 0; j < 4; j++)
          #pragma unroll
          for (int c = 0; c < 4; c++)
            acc[i][c] = FMA(x[i][j], w[j][c], acc[i][c]);
    }
    {
      f4 w = *(const f4*)(Wq + (size_t)128*128 + tc*4);
      #pragma unroll
      for (int i = 0; i < 8; i++) {
        float xv = xs[(tr*8+i)*132 + 128];
        #pragma unroll
        for (int c = 0; c < 4; c++) acc[i][c] = FMA(xv, w[c], acc[i][c]);
      }
    }
    #pragma unroll
    for (int i = 0; i < 8; i++) {
      f4 o;
      #pragma unroll
      for (int c = 0; c < 4; c++) o[c] = acc[i][c];
      *(f4*)(Q + (size_t)(r0 + tr*8 + i)*128 + tc*4) = o;
    }
  } else {
    const int r0 = (blockIdx.x - 500) * 64;
    for (int i = t; i < 64*32; i += 256) {
      int r = i >> 5, k4 = (i & 31) << 2;
      *(f4*)(xs + r*132 + k4) = *(const f4*)(Xn + (size_t)(r0+r)*128 + k4);
    }
    __syncthreads();
    float accK[8][4], accV[8][4];
    #pragma unroll
    for (int i = 0; i < 8; i++)
      #pragma unroll
      for (int c = 0; c < 4; c++) { accK[i][c] = 0.f; accV[i][c] = 0.f; }
    for (int k4 = 0; k4 < 128; k4 += 4) {
      f4 x[8], wk[4], wv[4];
      #pragma unroll
      for (int j = 0; j < 4; j++) {
        wk[j] = *(const f4*)(Wk + (size_t)(k4+j)*128 + tc*4);
        wv[j] = *(const f4*)(Wv + (size_t)(k4+j)*128 + tc*4);
      }
      #pragma unroll
      for (int i = 0; i < 8; i++) x[i] = *(const f4*)(xs + (tr*8+i)*132 + k4);
      #pragma unroll
      for (int i = 0; i < 8; i++)
        #pragma unroll
        for (int j = 0; j < 4; j++)
          #pragma unroll
          for (int c = 0; c < 4; c++) {
            accK[i][c] = FMA(x[i][j], wk[j][c], accK[i][c]);
            accV[i][c] = FMA(x[i][j], wv[j][c], accV[i][c]);
          }
    }
    #pragma unroll
    for (int i = 0; i < 8; i++) {
      f4 ok, ov;
      #pragma unroll
      for (int c = 0; c < 4; c++) { ok[c] = accK[i][c]; ov[c] = accV[i][c]; }
      *(f4*)(K_ + (size_t)(r0 + tr*8 + i)*128 + tc*4) = ok;
      *(f4*)(V_ + (size_t)(r0 + tr*8 + i)*128 + tc*4) = ov;
    }
  }
}

// ---------------- attention v12: v8 loop scaled to 512 thr / 64-row tile ----
// Grid 512 = 64 b x 8 ptiles, 512 threads = 8 waves, wave = head (t>>6),
// lane = row (t&63). Same per-thread loop as v8 (q16+out16+m/l, elementwise
// online softmax, reg-prefetch pipeline) but: every K/V ds_read is a
// 1-address wave broadcast; staging per output row is halved (2+2 f4
// prefetch regs); 2 blocks/CU x 8 waves resident.
__global__ __launch_bounds__(512, 4) void k_attn(
    const float* __restrict__ Q, const float* __restrict__ K_, const float* __restrict__ V_,
    const float* __restrict__ Msk, float* __restrict__ OC)
{
  __shared__ float ks[32*132];   // 16.9 KB
  __shared__ float vs[32*132];   // 16.9 KB
  __shared__ float mks[64*33];   // 8.4 KB
  const int blk = blockIdx.x;
  const int b  = blk >> 3;
  const int pt = blk & 7;
  const int p0 = pt * 64;
  const int t = threadIdx.x;
  const int h   = t >> 6;
  const int row = t & 63;
  const bool pvalid = (p0 + row) < PP;
  const int p = pvalid ? (p0 + row) : (PP - 1);

  f4 q0, q1, q2, q3;
  {
    const float* qrow = Q + ((size_t)b*PP + p)*128 + h*16;
    q0 = *(const f4*)(qrow);
    q1 = *(const f4*)(qrow + 4);
    q2 = *(const f4*)(qrow + 8);
    q3 = *(const f4*)(qrow + 12);
  }

  // staging coords: K/V 2 f4 each per thread; mask 4 scalars per thread
  const int mr = t >> 3, nq = (t & 7) << 2;     // mr 0..63, nq 0..28
  const int grow = min(p0 + mr, PP - 1);
  const float* gm = Msk + ((size_t)b*PP + grow)*NN;

  float m_r = -1e30f, l_r = 0.f;
  f4 o0 = {0.f,0.f,0.f,0.f}, o1 = o0, o2 = o0, o3 = o0;

  // prologue: chunk 0 -> regs
  f4 kpre[2], vpre[2]; float mk[4];
  #pragma unroll
  for (int u = 0; u < 2; u++) {
    int i = t + u*512;
    int n = i >> 5, d4 = (i & 31) << 2;
    kpre[u] = *(const f4*)(K_ + ((size_t)b*NN + n)*128 + d4);
    vpre[u] = *(const f4*)(V_ + ((size_t)b*NN + n)*128 + d4);
  }
  #pragma unroll
  for (int j = 0; j < 4; j++)
    mk[j] = (nq + j < NN) ? gm[nq + j] : -1e30f;

  for (int c0 = 0; c0 < NN; c0 += 32) {
    // write prefetched regs -> LDS
    #pragma unroll
    for (int u = 0; u < 2; u++) {
      int i = t + u*512;
      int n = i >> 5, d4 = (i & 31) << 2;
      *(f4*)(ks + n*132 + d4) = kpre[u];
      *(f4*)(vs + n*132 + d4) = vpre[u];
    }
    {
      float* dm = mks + mr*33 + nq;
      #pragma unroll
      for (int j = 0; j < 4; j++) dm[j] = mk[j];
    }
    __syncthreads();   // staging visible

    // issue next chunk's loads now; latency hides under compute below
    const int c1 = c0 + 32;
    if (c1 < NN) {
      #pragma unroll
      for (int u = 0; u < 2; u++) {
        int i = t + u*512;
        int n = i >> 5, d4 = (i & 31) << 2;
        int ng = c1 + n;
        f4 kv = {0.f,0.f,0.f,0.f}, vv = {0.f,0.f,0.f,0.f};
        if (ng < NN) {
          kv = *(const f4*)(K_ + ((size_t)b*NN + ng)*128 + d4);
          vv = *(const f4*)(V_ + ((size_t)b*NN + ng)*128 + d4);
        }
        kpre[u] = kv; vpre[u] = vv;
      }
      #pragma unroll
      for (int j = 0; j < 4; j++)
        mk[j] = (c1 + nq + j < NN) ? gm[c1 + nq + j] : -1e30f;
    }

    const float* ksh = ks + h*16;
    const float* vsh = vs + h*16;
    const float* mrw = mks + row*33;
    #pragma unroll
    for (int n = 0; n < 32; n++) {
      const float* kf = ksh + n*132;
      f4 k0 = *(const f4*)(kf);
      f4 k1 = *(const f4*)(kf + 4);
      f4 k2 = *(const f4*)(kf + 8);
      f4 k3 = *(const f4*)(kf + 12);
      float s = 0.f;
      #pragma unroll
      for (int d = 0; d < 4; d++) s = FMA(q0[d], k0[d], s);
      #pragma unroll
      for (int d = 0; d < 4; d++) s = FMA(q1[d], k1[d], s);
      #pragma unroll
      for (int d = 0; d < 4; d++) s = FMA(q2[d], k2[d], s);
      #pragma unroll
      for (int d = 0; d < 4; d++) s = FMA(q3[d], k3[d], s);
      s = FMA(s, 0.25f, mrw[n]);
      if (s > m_r) {   // rare after warmup (~ln(N) times per row)
        float cc = __expf(m_r - s);
        m_r = s;
        l_r *= cc;
        o0 *= cc; o1 *= cc; o2 *= cc; o3 *= cc;
      }
      float e = __expf(s - m_r);
      l_r += e;
      const float* vf = vsh + n*132;
      f4 v0 = *(const f4*)(vf);
      f4 v1 = *(const f4*)(vf + 4);
      f4 v2 = *(const f4*)(vf + 8);
      f4 v3 = *(const f4*)(vf + 12);
      #pragma unroll
      for (int d = 0; d < 4; d++) {
        o0[d] = FMA(e, v0[d], o0[d]);
        o1[d] = FMA(e, v1[d], o1[d]);
        o2[d] = FMA(e, v2[d], o2[d]);
        o3[d] = FMA(e, v3[d], o3[d]);
      }
    }
    __syncthreads();   // compute done; safe to overwrite LDS next iter
  }

  if (pvalid) {
    float inv = 1.f / l_r;
    float* orow = OC + ((size_t)b*PP + p)*128 + h*16;
    *(f4*)(orow)      = o0 * inv;
    *(f4*)(orow + 4)  = o1 * inv;
    *(f4*)(orow + 8)  = o2 * inv;
    *(f4*)(orow + 12) = o3 * inv;
  }
}

// ---------------- fused per-batch FFN chain ----------------
__global__ __launch_bounds__(256) void k_ffn(
    const float* __restrict__ OC, const float* __restrict__ Wn, const float* __restrict__ Bn,
    const float* __restrict__ Wn2, const float* __restrict__ Bn2,
    const float* __restrict__ Wm, const float* __restrict__ Bm,
    float* __restrict__ MH)
{
  __shared__ float xs[64*132];
  __shared__ float hs[64*132];
  const int blk = blockIdx.x; const int b = blk >> 3, rb = blk & 7;
  const int r0 = rb*64;
  const int nv = min(64, PP - r0);
  const int t = threadIdx.x;
  const int tr = t >> 5, tc = t & 31;
  const float* ocb = OC + (size_t)b*PP*128;
  for (int i = t; i < 64*32; i += 256) {
    int r = i >> 5, k4 = (i & 31) << 2;
    f4 v = {0.f,0.f,0.f,0.f};
    if (r < nv) v = *(const f4*)(ocb + (size_t)(r0+r)*128 + k4);
    *(f4*)(xs + r*132 + k4) = v;
  }
  __syncthreads();
  // GEMM1: relu(xs @ new[b] + bias)
  {
    const float* W1 = Wn + (size_t)b*16384;
    float acc[8][4];
    #pragma unroll
    for (int i = 0; i < 8; i++)
      #pragma unroll
      for (int c = 0; c < 4; c++) acc[i][c] = 0.f;
    for (int k4 = 0; k4 < 128; k4 += 4) {
      f4 x[8], w[4];
      #pragma unroll
      for (int j = 0; j < 4; j++) w[j] = *(const f4*)(W1 + (size_t)(k4+j)*128 + tc*4);
      #pragma unroll
      for (int i = 0; i < 8; i++) x[i] = *(const f4*)(xs + (tr*8+i)*132 + k4);
      #pragma unroll
      for (int i = 0; i < 8; i++)
        #pragma unroll
        for (int j = 0; j < 4; j++)
          #pragma unroll
          for (int c = 0; c < 4; c++)
            acc[i][c] = FMA(x[i][j], w[j][c], acc[i][c]);
    }
    f4 b1 = *(const f4*)(Bn + b*128 + tc*4);
    #pragma unroll
    for (int i = 0; i < 8; i++) {
      f4 o;
      #pragma unroll
      for (int c = 0; c < 4; c++) o[c] = fmaxf(acc[i][c] + b1[c], 0.f);
      *(f4*)(hs + (tr*8+i)*132 + tc*4) = o;
    }
  }
  __syncthreads();
  // GEMM2: hs @ new_2[b] + bias2 + residual(xs)
  float h2[8][4];
  {
    const float* W2 = Wn2 + (size_t)b*16384;
    float acc[8][4];
    #pragma unroll
    for (int i = 0; i < 8; i++)
      #pragma unroll
      for (int c = 0; c < 4; c++) acc[i][c] = 0.f;
    for (int k4 = 0; k4 < 128; k4 += 4) {
      f4 x[8], w[4];
      #pragma unroll
      for (int j = 0; j < 4; j++) w[j] = *(const f4*)(W2 + (size_t)(k4+j)*128 + tc*4);
      #pragma unroll
      for (int i = 0; i < 8; i++) x[i] = *(const f4*)(hs + (tr*8+i)*132 + k4);
      #pragma unroll
      for (int i = 0; i < 8; i++)
        #pragma unroll
        for (int j = 0; j < 4; j++)
          #pragma unroll
          for (int c = 0; c < 4; c++)
            acc[i][c] = FMA(x[i][j], w[j][c], acc[i][c]);
    }
    f4 b2 = *(const f4*)(Bn2 + b*128 + tc*4);
    #pragma unroll
    for (int i = 0; i < 8; i++)
      #pragma unroll
      for (int c = 0; c < 4; c++)
        h2[i][c] = acc[i][c] + b2[c] + xs[(tr*8+i)*132 + tc*4 + c];
  }
  __syncthreads();
  #pragma unroll
  for (int i = 0; i < 8; i++) {
    f4 o;
    #pragma unroll
    for (int c = 0; c < 4; c++) o[c] = h2[i][c];
    *(f4*)(hs + (tr*8+i)*132 + tc*4) = o;
  }
  __syncthreads();
  // GEMM3: hs @ mhc_W + mhc_b -> MH
  {
    float acc[8][4];
    #pragma unroll
    for (int i = 0; i < 8; i++)
      #pragma unroll
      for (int c = 0; c < 4; c++) acc[i][c] = 0.f;
    for (int k4 = 0; k4 < 128; k4 += 4) {
      f4 x[8], w[4];
      #pragma unroll
      for (int j = 0; j < 4; j++) w[j] = *(const f4*)(Wm + (size_t)(k4+j)*128 + tc*4);
      #pragma unroll
      for (int i = 0; i < 8; i++) x[i] = *(const f4*)(hs + (tr*8+i)*132 + k4);
      #pragma unroll
      for (int i = 0; i < 8; i++)
        #pragma unroll
        for (int j = 0; j < 4; j++)
          #pragma unroll
          for (int c = 0; c < 4; c++)
            acc[i][c] = FMA(x[i][j], w[j][c], acc[i][c]);
    }
    f4 b3 = *(const f4*)(Bm + tc*4);
    #pragma unroll
    for (int i = 0; i < 8; i++) {
      if (tr*8 + i < nv) {
        f4 o;
        #pragma unroll
        for (int c = 0; c < 4; c++) o[c] = acc[i][c] + b3[c];
        *(f4*)(MH + ((size_t)b*PP + r0 + tr*8 + i)*128 + tc*4) = o;
      }
    }
  }
}

// ---------------- final v2: reg-prefetch pipelined EN staging + FMA ---------
__global__ __launch_bounds__(256, 3) void k_final(
    const float* __restrict__ MH, const float* __restrict__ EN,
    const float* __restrict__ Msk, float* __restrict__ OUT)
{
  __shared__ float ms[32*132];   // 16.9 KB
  __shared__ float es[64*132];   // 33.8 KB
  const int blk = blockIdx.x; const int b = blk >> 4, rb = blk & 15;
  const int r0 = rb*32; const int nv = min(32, PP - r0);
  const int t = threadIdx.x;
  const int tr = t >> 5, tc = t & 31;
  const float* mhb = MH + (size_t)(b*PP + r0)*128;
  for (int i = t; i < 32*32; i += 256) {
    int r = i >> 5, k4 = (i & 31) << 2;
    f4 v = {0.f,0.f,0.f,0.f};
    if (r < nv) v = *(const f4*)(mhb + (size_t)r*128 + k4);
    *(f4*)(ms + r*132 + k4) = v;
  }
  const float* enb = EN + (size_t)b*NN*128;
  // prologue: tile 0 -> regs
  f4 epre[8];
  #pragma unroll
  for (int u = 0; u < 8; u++) {
    int i = t + u*256;
    int n = i >> 5, k4 = (i & 31) << 2;
    f4 v = {0.f,0.f,0.f,0.f};
    if (n < NN) v = *(const f4*)(enb + (size_t)n*128 + k4);
    epre[u] = v;
  }
  float s[8][4][2];
  #pragma unroll
  for (int nt = 0; nt < 8; nt++) {
    // write prefetched tile -> LDS
    #pragma unroll
    for (int u = 0; u < 8; u++) {
      int i = t + u*256;
      int n = i >> 5, k4 = (i & 31) << 2;
      *(f4*)(es + n*132 + k4) = epre[u];
    }
    __syncthreads();   // es (and, first iter, ms) visible
    // issue next tile's loads; latency hides under GEMM below
    if (nt < 7) {
      const int n1 = (nt+1)*64;
      #pragma unroll
      for (int u = 0; u < 8; u++) {
        int i = t + u*256;
        int n = i >> 5, k4 = (i & 31) << 2;
        f4 v = {0.f,0.f,0.f,0.f};
        if (n1 + n < NN) v = *(const f4*)(enb + (size_t)(n1+n)*128 + k4);
        epre[u] = v;
      }
    }
    float acc[4][2];
    #pragma unroll
    for (int i = 0; i < 4; i++) { acc[i][0] = 0.f; acc[i][1] = 0.f; }
    #pragma unroll 8
    for (int k4 = 0; k4 < 128; k4 += 4) {
      f4 x[4];
      #pragma unroll
      for (int i = 0; i < 4; i++) x[i] = *(const f4*)(ms + (tr*4+i)*132 + k4);
      f4 e0 = *(const f4*)(es + tc*132 + k4);
      f4 e1 = *(const f4*)(es + (tc+32)*132 + k4);
      #pragma unroll
      for (int i = 0; i < 4; i++)
        #pragma unroll
        for (int j = 0; j < 4; j++) {
          acc[i][0] = FMA(x[i][j], e0[j], acc[i][0]);
          acc[i][1] = FMA(x[i][j], e1[j], acc[i][1]);
        }
    }
    #pragma unroll
    for (int i = 0; i < 4; i++) {
      s[nt][i][0] = acc[i][0];
      s[nt][i][1] = acc[i][1];
    }
    __syncthreads();   // GEMM done; safe to overwrite es next iter
  }
  // clip + mask, in registers
  const float* mkb = Msk + (size_t)(b*PP + r0)*NN;
  #pragma unroll
  for (int nt = 0; nt < 8; nt++)
    #pragma unroll
    for (int i = 0; i < 4; i++)
      #pragma unroll
      for (int c = 0; c < 2; c++) {
        int r = tr*4 + i, n = nt*64 + tc + c*32;
        float val = -INFINITY;
        if (r < nv && n < NN) {
          // 10*tanh(s/sqrt(128)) = 10 - 20/(exp(s*2/sqrt(128)) + 1)  (NaN-free)
          float E = __expf(s[nt][i][c] * 0.17677669529663687f);
          val = 10.f - 20.f/(E + 1.f) + mkb[(size_t)r*NN + n];
        }
        s[nt][i][c] = val;
      }
  // per-row softmax: reduce across the 32 tc lanes (width 32 keeps tr pairs separate)
  float* ob = OUT + (size_t)(b*PP + r0)*NN;
  #pragma unroll
  for (int i = 0; i < 4; i++) {
    float m = -INFINITY;
    #pragma unroll
    for (int nt = 0; nt < 8; nt++)
      #pragma unroll
      for (int c = 0; c < 2; c++) m = fmaxf(m, s[nt][i][c]);
    #pragma unroll
    for (int o = 16; o > 0; o >>= 1) m = fmaxf(m, __shfl_xor(m, o, 32));
    float l = 0.f;
    #pragma unroll
    for (int nt = 0; nt < 8; nt++)
      #pragma unroll
      for (int c = 0; c < 2; c++) {
        float e_ = __expf(s[nt][i][c] - m);
        s[nt][i][c] = e_;
        l += e_;
      }
    #pragma unroll
    for (int o = 16; o > 0; o >>= 1) l += __shfl_xor(l, o, 32);
    const int r = tr*4 + i;
    if (r < nv) {
      float inv = 1.f / l;
      float* orow = ob + (size_t)r*NN;
      #pragma unroll
      for (int nt = 0; nt < 8; nt++)
        #pragma unroll
        for (int c = 0; c < 2; c++) {
          int n = nt*64 + tc + c*32;
          if (n < NN) orow[n] = s[nt][i][c] * inv;
        }
    }
  }
}

extern "C" void kernel_launch(void* const* d_in, const int* in_sizes, int n_in,
                              void* d_out, int out_size, void* d_ws, size_t ws_size,
                              hipStream_t stream) {
  const float* eln  = (const float*)d_in[0];
  const float* load = (const float*)d_in[1];
  const float* mask = (const float*)d_in[2];
  const float* en   = (const float*)d_in[3];
  const float* Wq   = (const float*)d_in[4];
  const float* Wk   = (const float*)d_in[5];
  const float* Wv   = (const float*)d_in[6];
  const float* Wm   = (const float*)d_in[7];
  const float* Bm   = (const float*)d_in[8];
  const float* Wn   = (const float*)d_in[9];
  const float* Bn   = (const float*)d_in[10];
  const float* Wn2  = (const float*)d_in[11];
  const float* Bn2  = (const float*)d_in[12];
  float* out = (float*)d_out;
  float* ws  = (float*)d_ws;
  float* Q   = ws;
  float* K_  = ws + 4096000;     // 64*500*128
  float* V_  = ws + 8200192;     // + 64*501*128
  float* OC  = ws + 12304384;    // + 64*501*128
  float* MH  = ws + 16400384;    // + 64*500*128
  hipLaunchKernelGGL(k_proj,  dim3(1001), dim3(256), 0, stream, eln, load, en, Wq, Wk, Wv, Q, K_, V_);
  hipLaunchKernelGGL(k_attn,  dim3(512),  dim3(512), 0, stream, Q, K_, V_, mask, OC);
  hipLaunchKernelGGL(k_ffn,   dim3(512),  dim3(256), 0, stream, OC, Wn, Bn, Wn2, Bn2, Wm, Bm, MH);
  hipLaunchKernelGGL(k_final, dim3(1024), dim3(256), 0, stream, MH, en, mask, out);
}